// Round 3
// baseline (111.949 us; speedup 1.0000x reference)
//
#include <hip/hip_runtime.h>
#include <hip/hip_bf16.h>
#include <math.h>

// (B, L, H, C) = (2, 512, 128, 25)
#define BB 2
#define LL 512
#define HH 128
#define CC 25
#define W4H (4*HH)

typedef __attribute__((ext_vector_type(8))) short short8;
typedef __attribute__((ext_vector_type(4))) float f32x4;

// ws layout:
//   T1b f32 [B*L][C]    @ float offset 0       : t1 + bias
//   T2b f32 [B*L][C]    @ float offset 25600   : t2
//   WfT bf16 [32][256]  @ byte offset 204800   : WfT[c][k] = (k<128 ? W3[c][k] : W4[c][k-128]), 0 for c>=25
#define T1_OFF 0
#define T2_OFF (BB*LL*CC)
#define WFT_BYTE_OFF (2*BB*LL*CC*4)

#define MTILE 64   // m rows per block (4 waves x 16)
#define LPB   8    // l rows per block
#define XP    132  // x2 LDS pitch in floats (528 B)

static __device__ __forceinline__ short f2bf(float f) {
    return __builtin_bit_cast(short, __float2bfloat16(f));
}

// grid (4, 25): blockIdx.y = c (wave-uniform -> W rows become scalar loads)
__global__ __launch_bounds__(256)
void prep_kernel(const float* __restrict__ x1, const float* __restrict__ x2,
                 const float* __restrict__ W, const float* __restrict__ bias,
                 float* __restrict__ ws)
{
    const int tid = threadIdx.x;
    const int c   = blockIdx.y;
    const int bl  = blockIdx.x * 256 + tid;

    // Pack W3|W4 transposed as bf16 (done by the 4 y==0 blocks, 8192 entries)
    if (blockIdx.y == 0) {
        unsigned short* wft = (unsigned short*)((char*)ws + WFT_BYTE_OFF);
        for (int idx = blockIdx.x * 256 + tid; idx < 32 * 256; idx += 4 * 256) {
            const int cc = idx >> 8;
            const int k  = idx & 255;
            float v = 0.f;
            if (cc < CC) v = (k < HH) ? W[(size_t)cc * W4H + 2*HH + k]
                                      : W[(size_t)cc * W4H + 3*HH + (k - HH)];
            wft[idx] = (unsigned short)f2bf(v);
        }
    }

    const float* w1  = W + (size_t)c * W4H;        // uniform -> s_load
    const float* w2  = w1 + HH;
    const float* xr1 = x1 + (size_t)bl * HH;
    const float* xr2 = x2 + (size_t)bl * HH;

    float s1a = 0.f, s1b = 0.f, s2a = 0.f, s2b = 0.f;
    #pragma unroll
    for (int i = 0; i < 32; i += 2) {
        const f32x4 a0 = *(const f32x4*)(xr1 + i*4);
        const f32x4 a1 = *(const f32x4*)(xr1 + i*4 + 4);
        const f32x4 b0 = *(const f32x4*)(xr2 + i*4);
        const f32x4 b1 = *(const f32x4*)(xr2 + i*4 + 4);
        const f32x4 u0 = *(const f32x4*)(w1 + i*4);
        const f32x4 u1 = *(const f32x4*)(w1 + i*4 + 4);
        const f32x4 v0 = *(const f32x4*)(w2 + i*4);
        const f32x4 v1 = *(const f32x4*)(w2 + i*4 + 4);
        #pragma unroll
        for (int j = 0; j < 4; ++j) {
            s1a = fmaf(a0[j], u0[j], s1a);
            s1b = fmaf(a1[j], u1[j], s1b);
            s2a = fmaf(b0[j], v0[j], s2a);
            s2b = fmaf(b1[j], v1[j], s2b);
        }
    }
    ws[T1_OFF + bl * CC + c] = s1a + s1b + bias[c];
    ws[T2_OFF + bl * CC + c] = s2a + s2b;
}

__global__ __launch_bounds__(256)
void biaffine_mfma(const float* __restrict__ x1, const float* __restrict__ x2,
                   const float* __restrict__ ws, float* __restrict__ out)
{
    __shared__ __align__(16) float x2s[MTILE * XP];
    __shared__ __align__(16) float x1s[LPB * HH];

    const int tid = threadIdx.x;
    const int b   = blockIdx.z;
    const int l0  = blockIdx.y * LPB;
    const int m0  = blockIdx.x * MTILE;

    const int lane = tid & 63;
    const int wv   = tid >> 6;      // wave 0..3
    const int q    = lane >> 4;     // k-group 0..3
    const int cn   = lane & 15;     // A-row (m) for input frags; D-col (c) for output

    // ---- persistent B fragments: Bf[tile][kk], k = kk*32 + q*8 + j, c = cn + 16*tile ----
    const unsigned short* wft = (const unsigned short*)((const char*)ws + WFT_BYTE_OFF);
    short8 Bf[2][8];
    #pragma unroll
    for (int t = 0; t < 2; ++t)
        #pragma unroll
        for (int kk = 0; kk < 8; ++kk)
            Bf[t][kk] = *(const short8*)(wft + ((cn + 16*t) * 256 + kk * 32 + q * 8));

    // ---- stage x2 tile (64x128) and x1 rows (8x128) ----
    {
        const float* sx2 = x2 + ((size_t)b * LL + m0) * HH;
        #pragma unroll
        for (int i = 0; i < 8; ++i) {
            const int idx = i * 256 + tid;     // float4 index, 2048 total
            const int r   = idx >> 5;
            const int c4  = idx & 31;
            f32x4 v = *(const f32x4*)(sx2 + r * HH + c4 * 4);
            *(f32x4*)(&x2s[r * XP + c4 * 4]) = v;
        }
        const float* sx1 = x1 + ((size_t)b * LL + l0) * HH;
        f32x4 v = *(const f32x4*)(sx1 + tid * 4);
        *(f32x4*)(&x1s[tid * 4]) = v;
    }
    __syncthreads();

    const int mrowA = wv * 16 + cn;
    const float* px2 = &x2s[mrowA * XP];

    f32x4 acc0[LPB], acc1[LPB];
    #pragma unroll
    for (int l = 0; l < LPB; ++l) {
        acc0[l] = (f32x4){0.f, 0.f, 0.f, 0.f};
        acc1[l] = (f32x4){0.f, 0.f, 0.f, 0.f};
    }

    // ---- k-slice outer, l inner: x2 fragments loaded once, reused for all 8 l ----
    #pragma unroll
    for (int hh = 0; hh < 4; ++hh) {
        const int hb = hh * 32 + q * 8;
        const f32x4 b0 = *(const f32x4*)(px2 + hb);
        const f32x4 b1 = *(const f32x4*)(px2 + hb + 4);
        #pragma unroll
        for (int l = 0; l < LPB; ++l) {
            const float* px1 = &x1s[l * HH];
            const f32x4 a0 = *(const f32x4*)(px1 + hb);       // wave-uniform per q
            const f32x4 a1 = *(const f32x4*)(px1 + hb + 4);
            short8 Ap, Ad;
            #pragma unroll
            for (int j = 0; j < 4; ++j) {
                Ap[j]     = f2bf(a0[j] * b0[j]);
                Ad[j]     = f2bf(fabsf(a0[j] - b0[j]));
                Ap[4 + j] = f2bf(a1[j] * b1[j]);
                Ad[4 + j] = f2bf(fabsf(a1[j] - b1[j]));
            }
            acc0[l] = __builtin_amdgcn_mfma_f32_16x16x32_bf16(Ap, Bf[0][hh],     acc0[l], 0, 0, 0);
            acc1[l] = __builtin_amdgcn_mfma_f32_16x16x32_bf16(Ap, Bf[1][hh],     acc1[l], 0, 0, 0);
            acc0[l] = __builtin_amdgcn_mfma_f32_16x16x32_bf16(Ad, Bf[0][hh + 4], acc0[l], 0, 0, 0);
            acc1[l] = __builtin_amdgcn_mfma_f32_16x16x32_bf16(Ad, Bf[1][hh + 4], acc1[l], 0, 0, 0);
        }
    }

    // ---- epilogue ----
    const float* Tb1 = ws + T1_OFF;
    const float* Tb2 = ws + T2_OFF;

    float t2a[4], t2b[4];
    #pragma unroll
    for (int r = 0; r < 4; ++r) {
        const int mg = m0 + wv * 16 + q * 4 + r;
        t2a[r] = Tb2[((size_t)b * LL + mg) * CC + cn];
        t2b[r] = (cn + 16 < CC) ? Tb2[((size_t)b * LL + mg) * CC + cn + 16] : 0.f;
    }

    #pragma unroll
    for (int l = 0; l < LPB; ++l) {
        const int lg = l0 + l;
        const float t1a = Tb1[((size_t)b * LL + lg) * CC + cn];
        const float t1b = (cn + 16 < CC) ? Tb1[((size_t)b * LL + lg) * CC + cn + 16] : 0.f;
        #pragma unroll
        for (int r = 0; r < 4; ++r) {
            const int mg = m0 + wv * 16 + q * 4 + r;
            float* o = out + (((size_t)b * LL + lg) * LL + mg) * CC;
            o[cn] = acc0[l][r] + t1a + t2a[r];
            if (cn + 16 < CC) o[cn + 16] = acc1[l][r] + t1b + t2b[r];
        }
    }
}

extern "C" void kernel_launch(void* const* d_in, const int* in_sizes, int n_in,
                              void* d_out, int out_size, void* d_ws, size_t ws_size,
                              hipStream_t stream) {
    const float* x1   = (const float*)d_in[0];
    const float* x2   = (const float*)d_in[1];
    const float* W    = (const float*)d_in[2];
    const float* bias = (const float*)d_in[3];
    float* out = (float*)d_out;
    float* ws  = (float*)d_ws;

    dim3 pgrid(BB * LL / 256, CC);          // (4, 25)
    prep_kernel<<<pgrid, 256, 0, stream>>>(x1, x2, W, bias, ws);

    dim3 grid(LL / MTILE, LL / LPB, BB);    // (8, 64, 2) = 1024 blocks
    biaffine_mfma<<<grid, 256, 0, stream>>>(x1, x2, ws, out);
}

// Round 5
// 102.239 us; speedup vs baseline: 1.0950x; 1.0950x over previous
//
#include <hip/hip_runtime.h>
#include <hip/hip_bf16.h>
#include <math.h>

// (B, L, H, C) = (2, 512, 128, 25)
#define BB 2
#define LL 512
#define HH 128
#define CC 25
#define W4H (4*HH)

typedef __attribute__((ext_vector_type(4))) float    f32x4;
typedef __attribute__((ext_vector_type(8))) _Float16 half8;
typedef __attribute__((ext_vector_type(2))) _Float16 half2t;
typedef __attribute__((ext_vector_type(4))) unsigned uint4v;

// ws layout:
//   T1b f32 [B*L][C]     @ float offset 0       : t1 + bias
//   T2b f32 [B*L][C]     @ float offset 25600   : t2
//   WfT f16 [32][256]    @ byte offset 204800   : WfT[c][k] = (k<128 ? W3[c][k] : W4[c][k-128]), 0 for c>=25
#define T1_OFF 0
#define T2_OFF (BB*LL*CC)
#define WFT_BYTE_OFF (2*BB*LL*CC*4)

#define MTILE 64    // m rows per block (4 waves x 16)
#define LPB   8     // l rows per block
#define XPH   136   // f16 LDS pitch in halves (272 B rows, 16B-aligned, bank-spread)

static __device__ __forceinline__ half8 habs8(half8 x) {
    uint4v u = __builtin_bit_cast(uint4v, x);
    u &= 0x7FFF7FFFu;
    return __builtin_bit_cast(half8, u);
}

static __device__ __forceinline__ half2t pkrtz(float a, float b) {
    return __builtin_bit_cast(half2t, __builtin_amdgcn_cvt_pkrtz(a, b));
}

union H4 { half2t h2[2]; unsigned long long u64; };

// grid (4, 25): blockIdx.y = c (wave-uniform -> W rows become scalar loads)
__global__ __launch_bounds__(256)
void prep_kernel(const float* __restrict__ x1, const float* __restrict__ x2,
                 const float* __restrict__ W, const float* __restrict__ bias,
                 float* __restrict__ ws)
{
    const int tid = threadIdx.x;
    const int c   = blockIdx.y;
    const int bl  = blockIdx.x * 256 + tid;

    // Pack W3|W4 transposed as f16 (done by the 4 y==0 blocks, 8192 entries)
    if (blockIdx.y == 0) {
        _Float16* wft = (_Float16*)((char*)ws + WFT_BYTE_OFF);
        for (int idx = blockIdx.x * 256 + tid; idx < 32 * 256; idx += 4 * 256) {
            const int cc = idx >> 8;
            const int k  = idx & 255;
            float v = 0.f;
            if (cc < CC) v = (k < HH) ? W[(size_t)cc * W4H + 2*HH + k]
                                      : W[(size_t)cc * W4H + 3*HH + (k - HH)];
            wft[idx] = (_Float16)v;
        }
    }

    const float* w1  = W + (size_t)c * W4H;        // uniform -> s_load
    const float* w2  = w1 + HH;
    const float* xr1 = x1 + (size_t)bl * HH;
    const float* xr2 = x2 + (size_t)bl * HH;

    float s1a = 0.f, s1b = 0.f, s2a = 0.f, s2b = 0.f;
    #pragma unroll
    for (int i = 0; i < 32; i += 2) {
        const f32x4 a0 = *(const f32x4*)(xr1 + i*4);
        const f32x4 a1 = *(const f32x4*)(xr1 + i*4 + 4);
        const f32x4 b0 = *(const f32x4*)(xr2 + i*4);
        const f32x4 b1 = *(const f32x4*)(xr2 + i*4 + 4);
        const f32x4 u0 = *(const f32x4*)(w1 + i*4);
        const f32x4 u1 = *(const f32x4*)(w1 + i*4 + 4);
        const f32x4 v0 = *(const f32x4*)(w2 + i*4);
        const f32x4 v1 = *(const f32x4*)(w2 + i*4 + 4);
        #pragma unroll
        for (int j = 0; j < 4; ++j) {
            s1a = fmaf(a0[j], u0[j], s1a);
            s1b = fmaf(a1[j], u1[j], s1b);
            s2a = fmaf(b0[j], v0[j], s2a);
            s2b = fmaf(b1[j], v1[j], s2b);
        }
    }
    ws[T1_OFF + bl * CC + c] = s1a + s1b + bias[c];
    ws[T2_OFF + bl * CC + c] = s2a + s2b;
}

__global__ __launch_bounds__(256)
void biaffine_mfma(const float* __restrict__ x1, const float* __restrict__ x2,
                   const float* __restrict__ ws, float* __restrict__ out)
{
    __shared__ __align__(16) _Float16 x2h[MTILE * XPH];   // 17408 B
    __shared__ __align__(16) _Float16 x1h[LPB * XPH];     //  2176 B

    const int tid = threadIdx.x;
    const int b   = blockIdx.z;
    const int l0  = blockIdx.y * LPB;
    const int m0  = blockIdx.x * MTILE;

    const int lane = tid & 63;
    const int wv   = tid >> 6;      // wave 0..3
    const int q    = lane >> 4;     // k-group 0..3
    const int cn   = lane & 15;     // A-row (m) for input frags; D-col (c) for output

    // ---- persistent B fragments: Bf[tile][kk], k = kk*32 + q*8 + j, c = cn + 16*tile ----
    const _Float16* wft = (const _Float16*)((const char*)ws + WFT_BYTE_OFF);
    half8 Bf[2][8];
    #pragma unroll
    for (int t = 0; t < 2; ++t)
        #pragma unroll
        for (int kk = 0; kk < 8; ++kk)
            Bf[t][kk] = *(const half8*)(wft + ((cn + 16*t) * 256 + kk * 32 + q * 8));

    // ---- stage x2 tile (64x128) and x1 rows (8x128), converting f32 -> f16 ----
    {
        const float* sx2 = x2 + ((size_t)b * LL + m0) * HH;
        #pragma unroll
        for (int i = 0; i < 8; ++i) {
            const int idx = i * 256 + tid;     // f32x4-chunk index, 2048 total
            const int r   = idx >> 5;          // row 0..63
            const int c4  = idx & 31;          // chunk within row
            const f32x4 v = *(const f32x4*)(sx2 + r * HH + c4 * 4);
            H4 h;
            h.h2[0] = pkrtz(v[0], v[1]);
            h.h2[1] = pkrtz(v[2], v[3]);
            *(unsigned long long*)(&x2h[r * XPH + c4 * 4]) = h.u64;
        }
        const float* sx1 = x1 + ((size_t)b * LL + l0) * HH;
        const int r  = tid >> 5;               // row 0..7
        const int c4 = tid & 31;
        const f32x4 v = *(const f32x4*)(sx1 + r * HH + c4 * 4);
        H4 h;
        h.h2[0] = pkrtz(v[0], v[1]);
        h.h2[1] = pkrtz(v[2], v[3]);
        *(unsigned long long*)(&x1h[r * XPH + c4 * 4]) = h.u64;
    }
    __syncthreads();

    // ---- register-cache this lane's x2 fragments (one per k-slice) ----
    const int mrowA = wv * 16 + cn;
    half8 X2f[4];
    #pragma unroll
    for (int hh = 0; hh < 4; ++hh)
        X2f[hh] = *(const half8*)(&x2h[mrowA * XPH + hh * 32 + q * 8]);

    // ---- t2 is l-invariant: hoist per-output-row loads (D row = q*4 + r) ----
    const float* Tb1 = ws + T1_OFF;
    const float* Tb2 = ws + T2_OFF;
    float t2a[4], t2b[4];
    #pragma unroll
    for (int r = 0; r < 4; ++r) {
        const int mg = m0 + wv * 16 + q * 4 + r;
        t2a[r] = Tb2[((size_t)b * LL + mg) * CC + cn];
        t2b[r] = (cn + 16 < CC) ? Tb2[((size_t)b * LL + mg) * CC + cn + 16] : 0.f;
    }

    // ---- l outer, per-l epilogue: acc lives only inside the iteration ----
    #pragma unroll
    for (int l = 0; l < LPB; ++l) {
        const int lg = l0 + l;
        const float t1a = Tb1[((size_t)b * LL + lg) * CC + cn];
        const float t1b = (cn + 16 < CC) ? Tb1[((size_t)b * LL + lg) * CC + cn + 16] : 0.f;

        f32x4 acc0 = {0.f, 0.f, 0.f, 0.f};
        f32x4 acc1 = {0.f, 0.f, 0.f, 0.f};

        #pragma unroll
        for (int hh = 0; hh < 4; ++hh) {
            const half8 a  = *(const half8*)(&x1h[l * XPH + hh * 32 + q * 8]); // broadcast
            const half8 bq = X2f[hh];
            const half8 Ap = a * bq;          // 4x v_pk_mul_f16
            const half8 Ad = habs8(a - bq);   // 4x v_pk_sub + 4x v_and
            acc0 = __builtin_amdgcn_mfma_f32_16x16x32_f16(Ap, Bf[0][hh],     acc0, 0, 0, 0);
            acc1 = __builtin_amdgcn_mfma_f32_16x16x32_f16(Ap, Bf[1][hh],     acc1, 0, 0, 0);
            acc0 = __builtin_amdgcn_mfma_f32_16x16x32_f16(Ad, Bf[0][hh + 4], acc0, 0, 0, 0);
            acc1 = __builtin_amdgcn_mfma_f32_16x16x32_f16(Ad, Bf[1][hh + 4], acc1, 0, 0, 0);
        }

        #pragma unroll
        for (int r = 0; r < 4; ++r) {
            const int mg = m0 + wv * 16 + q * 4 + r;
            float* o = out + (((size_t)b * LL + lg) * LL + mg) * CC;
            o[cn] = acc0[r] + t1a + t2a[r];
            if (cn + 16 < CC) o[cn + 16] = acc1[r] + t1b + t2b[r];
        }
    }
}

extern "C" void kernel_launch(void* const* d_in, const int* in_sizes, int n_in,
                              void* d_out, int out_size, void* d_ws, size_t ws_size,
                              hipStream_t stream) {
    const float* x1   = (const float*)d_in[0];
    const float* x2   = (const float*)d_in[1];
    const float* W    = (const float*)d_in[2];
    const float* bias = (const float*)d_in[3];
    float* out = (float*)d_out;
    float* ws  = (float*)d_ws;

    dim3 pgrid(BB * LL / 256, CC);          // (4, 25)
    prep_kernel<<<pgrid, 256, 0, stream>>>(x1, x2, W, bias, ws);

    dim3 grid(LL / MTILE, LL / LPB, BB);    // (8, 64, 2) = 1024 blocks
    biaffine_mfma<<<grid, 256, 0, stream>>>(x1, x2, ws, out);
}

// Round 6
// 92.333 us; speedup vs baseline: 1.2125x; 1.1073x over previous
//
#include <hip/hip_runtime.h>
#include <hip/hip_bf16.h>
#include <math.h>

// (B, L, H, C) = (2, 512, 128, 25)
#define BB 2
#define LL 512
#define HH 128
#define CC 25
#define W4H (4*HH)

typedef __attribute__((ext_vector_type(4))) float    f32x4;
typedef __attribute__((ext_vector_type(8))) _Float16 half8;
typedef __attribute__((ext_vector_type(2))) _Float16 half2t;
typedef __attribute__((ext_vector_type(4))) unsigned uint4v;

#define MTILE 64    // m rows per block (4 waves x 16)
#define LPB   8     // l rows per block
#define XPH   136   // f16 LDS pitch in halves (272 B rows)

static __device__ __forceinline__ half8 habs8(half8 x) {
    uint4v u = __builtin_bit_cast(uint4v, x);
    u &= 0x7FFF7FFFu;
    return __builtin_bit_cast(half8, u);
}
static __device__ __forceinline__ half2t pkrtz(float a, float b) {
    return __builtin_bit_cast(half2t, __builtin_amdgcn_cvt_pkrtz(a, b));
}
union H4 { half2t h2[2]; unsigned long long u64; };
union H8 { half2t h2[4]; uint4v u4; half8 h8; };

// Single fused kernel. Features per (l,m): f[k], k in [0,512):
//   k<128: x1*x2 (W3) | 128<=k<256: |x1-x2| (W4) | 256<=k<384: x1 (W1) | else: x2 (W2)
// W column for feature k: (k+256) & 511  (W layout [c][W1|W2|W3|W4] is a rotation).
__global__ __launch_bounds__(256)
void biaffine_fused(const float* __restrict__ x1, const float* __restrict__ x2,
                    const float* __restrict__ W, const float* __restrict__ bias,
                    float* __restrict__ out)
{
    // Pre-swizzled W fragments: frag id fid = (kk*2 + t)*64 + lane, half8 each.
    __shared__ __align__(16) _Float16 wfrag[2048 * 8];      // 32768 B
    __shared__ __align__(16) _Float16 x2h[MTILE * XPH];     // 17408 B
    __shared__ __align__(16) _Float16 x1h[LPB * XPH];       //  2176 B

    const int tid = threadIdx.x;
    const int b   = blockIdx.z;
    const int l0  = blockIdx.y * LPB;
    const int m0  = blockIdx.x * MTILE;

    const int lane = tid & 63;
    const int wv   = tid >> 6;      // wave 0..3
    const int q    = lane >> 4;     // k-group 0..3
    const int cn   = lane & 15;     // A-row (m) for frags; D-col (c) for output

    // ---- stage W fragments (f32 -> f16, fragment-order layout) ----
    #pragma unroll
    for (int i = 0; i < 8; ++i) {
        const int fid = i * 256 + tid;
        const int ln  = fid & 63;
        const int t   = (fid >> 6) & 1;
        const int kk  = fid >> 7;                 // 0..15
        const int c   = (ln & 15) + 16 * t;
        const int k0  = kk * 32 + ((ln >> 4) << 3);
        const int wc  = (k0 + 256) & 511;
        H8 h; h.u4 = (uint4v){0u, 0u, 0u, 0u};
        if (c < CC) {
            const f32x4 v0 = *(const f32x4*)(W + (size_t)c * W4H + wc);
            const f32x4 v1 = *(const f32x4*)(W + (size_t)c * W4H + wc + 4);
            h.h2[0] = pkrtz(v0[0], v0[1]);
            h.h2[1] = pkrtz(v0[2], v0[3]);
            h.h2[2] = pkrtz(v1[0], v1[1]);
            h.h2[3] = pkrtz(v1[2], v1[3]);
        }
        *(uint4v*)(&wfrag[fid * 8]) = h.u4;
    }

    // ---- stage x2 tile (64x128) and x1 rows (8x128), f32 -> f16 ----
    {
        const float* sx2 = x2 + ((size_t)b * LL + m0) * HH;
        #pragma unroll
        for (int i = 0; i < 8; ++i) {
            const int idx = i * 256 + tid;
            const int r   = idx >> 5;
            const int c4  = idx & 31;
            const f32x4 v = *(const f32x4*)(sx2 + r * HH + c4 * 4);
            H4 h;
            h.h2[0] = pkrtz(v[0], v[1]);
            h.h2[1] = pkrtz(v[2], v[3]);
            *(unsigned long long*)(&x2h[r * XPH + c4 * 4]) = h.u64;
        }
        const float* sx1 = x1 + ((size_t)b * LL + l0) * HH;
        const int r  = tid >> 5;
        const int c4 = tid & 31;
        const f32x4 v = *(const f32x4*)(sx1 + r * HH + c4 * 4);
        H4 h;
        h.h2[0] = pkrtz(v[0], v[1]);
        h.h2[1] = pkrtz(v[2], v[3]);
        *(unsigned long long*)(&x1h[r * XPH + c4 * 4]) = h.u64;
    }
    __syncthreads();

    // ---- persistent B fragments from LDS (lane-contiguous, conflict-free) ----
    half8 Bf0[16], Bf1[16];
    #pragma unroll
    for (int kk = 0; kk < 16; ++kk) {
        Bf0[kk] = *(const half8*)(&wfrag[((kk * 2 + 0) * 64 + lane) * 8]);
        Bf1[kk] = *(const half8*)(&wfrag[((kk * 2 + 1) * 64 + lane) * 8]);
    }

    // ---- register-cache this lane's x2 fragments ----
    const int mrowA = wv * 16 + cn;
    half8 X2f[4];
    #pragma unroll
    for (int hh = 0; hh < 4; ++hh)
        X2f[hh] = *(const half8*)(&x2h[mrowA * XPH + hh * 32 + q * 8]);

    const float ba = bias[cn];
    const float bb = (cn + 16 < CC) ? bias[cn + 16] : 0.f;

    // ---- main loop: per l, 32 MFMA over K=512, per-l epilogue ----
    #pragma unroll
    for (int l = 0; l < LPB; ++l) {
        f32x4 acc0 = {0.f, 0.f, 0.f, 0.f};
        f32x4 acc1 = {0.f, 0.f, 0.f, 0.f};

        #pragma unroll
        for (int hh = 0; hh < 4; ++hh) {
            const half8 a  = *(const half8*)(&x1h[l * XPH + hh * 32 + q * 8]); // broadcast
            const half8 bq = X2f[hh];
            const half8 Ap = a * bq;
            const half8 Ad = habs8(a - bq);
            // products: kk = hh
            acc0 = __builtin_amdgcn_mfma_f32_16x16x32_f16(Ap, Bf0[hh],      acc0, 0, 0, 0);
            acc1 = __builtin_amdgcn_mfma_f32_16x16x32_f16(Ap, Bf1[hh],      acc1, 0, 0, 0);
            // abs-diffs: kk = 4 + hh
            acc0 = __builtin_amdgcn_mfma_f32_16x16x32_f16(Ad, Bf0[4 + hh],  acc0, 0, 0, 0);
            acc1 = __builtin_amdgcn_mfma_f32_16x16x32_f16(Ad, Bf1[4 + hh],  acc1, 0, 0, 0);
            // x1 alone (t1): kk = 8 + hh, A-rows all equal (broadcast)
            acc0 = __builtin_amdgcn_mfma_f32_16x16x32_f16(a,  Bf0[8 + hh],  acc0, 0, 0, 0);
            acc1 = __builtin_amdgcn_mfma_f32_16x16x32_f16(a,  Bf1[8 + hh],  acc1, 0, 0, 0);
            // x2 alone (t2): kk = 12 + hh
            acc0 = __builtin_amdgcn_mfma_f32_16x16x32_f16(bq, Bf0[12 + hh], acc0, 0, 0, 0);
            acc1 = __builtin_amdgcn_mfma_f32_16x16x32_f16(bq, Bf1[12 + hh], acc1, 0, 0, 0);
        }

        const int lg = l0 + l;
        #pragma unroll
        for (int r = 0; r < 4; ++r) {
            const int mg = m0 + wv * 16 + q * 4 + r;
            float* o = out + (((size_t)b * LL + lg) * LL + mg) * CC;
            o[cn] = acc0[r] + ba;
            if (cn + 16 < CC) o[cn + 16] = acc1[r] + bb;
        }
    }
}

extern "C" void kernel_launch(void* const* d_in, const int* in_sizes, int n_in,
                              void* d_out, int out_size, void* d_ws, size_t ws_size,
                              hipStream_t stream) {
    const float* x1   = (const float*)d_in[0];
    const float* x2   = (const float*)d_in[1];
    const float* W    = (const float*)d_in[2];
    const float* bias = (const float*)d_in[3];
    float* out = (float*)d_out;

    dim3 grid(LL / MTILE, LL / LPB, BB);    // (8, 64, 2) = 1024 blocks
    biaffine_fused<<<grid, 256, 0, stream>>>(x1, x2, W, bias, out);
}